// Round 10
// baseline (493.147 us; speedup 1.0000x reference)
//
#include <hip/hip_runtime.h>
#include <math.h>

#define DIM 768
#define NH 12
#define HIDDEN 3072
#define BB 16
#define TT 577
#define TPAD 640
#define BT (BB*TT)      // 9232
#define MPAD 9344       // 73*128

typedef _Float16 f16x8 __attribute__((ext_vector_type(8)));
typedef __attribute__((ext_vector_type(4))) float f32x4;

// ---------------- LayerNorm -> fp16 plane (4-way pre-swizzled) ----------------
__global__ __launch_bounds__(256) void ln_kernel(const float* __restrict__ x,
                                                 const float* __restrict__ w,
                                                 const float* __restrict__ b,
                                                 _Float16* __restrict__ oh) {
    int row = blockIdx.x;
    const float* xr = x + (size_t)row * DIM;
    int t = threadIdx.x;
    float v0 = xr[t], v1 = xr[t + 256], v2 = xr[t + 512];
    float s = v0 + v1 + v2;
    float sq = v0 * v0 + v1 * v1 + v2 * v2;
    __shared__ float red[8];
    int lane = t & 63, wid = t >> 6;
    #pragma unroll
    for (int off = 32; off; off >>= 1) {
        s  += __shfl_down(s, off);
        sq += __shfl_down(sq, off);
    }
    if (lane == 0) { red[wid] = s; red[4 + wid] = sq; }
    __syncthreads();
    if (t == 0) {
        float ts = red[0] + red[1] + red[2] + red[3];
        float tq = red[4] + red[5] + red[6] + red[7];
        float mu = ts * (1.0f / DIM);
        float var = tq * (1.0f / DIM) - mu * mu;
        red[0] = mu;
        red[1] = rsqrtf(var + 1e-6f);
    }
    __syncthreads();
    float mu = red[0], rstd = red[1];
    int sw = (row & 3) << 3;   // 4-way: permutes k-bits 3-4, stays within 32-chunk
    size_t ro = (size_t)row * DIM;
    #pragma unroll
    for (int e = 0; e < 3; ++e) {
        int c = t + e * 256;
        float v = (e == 0 ? v0 : (e == 1 ? v1 : v2));
        float val = (v - mu) * rstd * w[c] + b[c];
        oh[ro + (c ^ sw)] = (_Float16)val;
    }
}

// -------- weight convert: fp32 [K][N] -> fp16 [N][K], 4-way pre-swizzled --------
__global__ __launch_bounds__(256) void convert_wT(const float* __restrict__ src,
                                                  _Float16* __restrict__ dh,
                                                  int K, int N) {
    int n = blockIdx.x * 64 + (threadIdx.x & 63);
    int k0 = blockIdx.y * 32 + (threadIdx.x >> 6) * 8;
    f16x8 h8;
    #pragma unroll
    for (int j = 0; j < 8; ++j) h8[j] = (_Float16)src[(size_t)(k0 + j) * N + n];
    *(f16x8*)&dh[(size_t)n * K + (k0 ^ ((n & 3) << 3))] = h8;
}

// ---------------- fp16 MFMA GEMM, BK=32 double-buffered (32 KiB LDS) ----------------
// A [Mpad][K], B [N][K] fp16, both pre-swizzled (k ^ ((row&3)<<3)).
// EPI: 1 = GELU -> fp16 plane, 2 = +resid fp32 out, 3 = QKV -> attention planes
template<int EPI>
__global__ __launch_bounds__(256, 4) void gemm_mfma(
    const _Float16* __restrict__ A, const _Float16* __restrict__ B,
    const float* __restrict__ bias, const float* __restrict__ resid,
    float* __restrict__ C, _Float16* __restrict__ O,
    _Float16* __restrict__ pQ, _Float16* __restrict__ pK, _Float16* __restrict__ pVT,
    int M, int N, int K) {
    __shared__ _Float16 lds[2][2][128][32];  // [dbuf][A/B][128][32] = 32 KiB
    int tid = threadIdx.x;
    int wid = tid >> 6, lane = tid & 63;
    int m0 = blockIdx.y * 128, n0 = blockIdx.x * 128;
    int wr = wid >> 1, wc = wid & 1;

    // wave wid stages 64 rows x 32 cols (4 issues x 1 KiB, linear LDS dest)
    const _Float16* src = (wid < 2) ? A : B;
    int srow0 = ((wid < 2) ? m0 : n0) + (wid & 1) * 64;
    const _Float16* gbase = src + (size_t)(srow0 + (lane >> 2)) * K + (lane & 3) * 8;
    _Float16* lb[2] = { &lds[0][wid >> 1][(wid & 1) * 64][0],
                        &lds[1][wid >> 1][(wid & 1) * 64][0] };

    f32x4 acc[4][4];
    #pragma unroll
    for (int i = 0; i < 4; ++i)
        #pragma unroll
        for (int j = 0; j < 4; ++j) acc[i][j] = (f32x4)0.0f;

    const int nk = K >> 5;
    // prologue: stage k-step 0 into buf 0
    #pragma unroll
    for (int i = 0; i < 4; ++i)
        __builtin_amdgcn_global_load_lds(
            (const __attribute__((address_space(1))) void*)(gbase + (size_t)i * 16 * K),
            (__attribute__((address_space(3))) void*)(lb[0] + i * 512), 16, 0, 0);
    __syncthreads();

    int cur = 0;
    for (int ks = 0; ks < nk; ++ks) {
        // prefetch next k-step into the other buffer (hides under MFMA)
        if (ks + 1 < nk) {
            int k0 = (ks + 1) << 5;
            #pragma unroll
            for (int i = 0; i < 4; ++i)
                __builtin_amdgcn_global_load_lds(
                    (const __attribute__((address_space(1))) void*)(gbase + (size_t)i * 16 * K + k0),
                    (__attribute__((address_space(3))) void*)(lb[cur ^ 1] + i * 512), 16, 0, 0);
        }
        // compute current buffer: 8 ds_read_b128 + 16 MFMA
        {
            int so = (((lane >> 4) ^ (lane & 3)) << 3);
            f16x8 af[4], bf[4];
            #pragma unroll
            for (int m = 0; m < 4; ++m)
                af[m] = *(const f16x8*)&lds[cur][0][wr * 64 + m * 16 + (lane & 15)][so];
            #pragma unroll
            for (int n = 0; n < 4; ++n)
                bf[n] = *(const f16x8*)&lds[cur][1][wc * 64 + n * 16 + (lane & 15)][so];
            #pragma unroll
            for (int m = 0; m < 4; ++m)
                #pragma unroll
                for (int n = 0; n < 4; ++n)
                    acc[m][n] = __builtin_amdgcn_mfma_f32_16x16x32_f16(af[m], bf[n], acc[m][n], 0, 0, 0);
        }
        __syncthreads();
        cur ^= 1;
    }

    // epilogue: C row = (lane>>4)*4 + reg, col = lane&15
    int rbase = m0 + wr * 64 + (lane >> 4) * 4;
    int cbase = n0 + wc * 64 + (lane & 15);
    #pragma unroll
    for (int mi = 0; mi < 4; ++mi) {
        #pragma unroll
        for (int ni = 0; ni < 4; ++ni) {
            int c = cbase + ni * 16;
            float bsv = bias[c];
            #pragma unroll
            for (int r4 = 0; r4 < 4; ++r4) {
                int r = rbase + mi * 16 + r4;
                if (r >= M) continue;
                float v = acc[mi][ni][r4] + bsv;
                if (EPI == 1) {
                    // tanh-form GELU: |err| < 4e-4
                    v = v / (1.0f + __expf(-1.5957691216f * (v + 0.044715f * v * v * v)));
                    O[(size_t)r * N + (c ^ ((r & 3) << 3))] = (_Float16)v;
                } else if (EPI == 2) {
                    v += resid[(size_t)r * N + c];
                    C[(size_t)r * N + c] = v;
                } else {  // EPI == 3: scatter to attention planes
                    int b_ = r / TT, t_ = r - b_ * TT;
                    int which = c / DIM, cc = c - which * DIM;
                    int head = cc >> 6, d = cc & 63;
                    size_t bh = (size_t)b_ * NH + head;
                    if (which == 0) {
                        pQ[(bh * TPAD + t_) * 64 + d] = (_Float16)(v * 0.125f);
                    } else if (which == 1) {
                        pK[(bh * TPAD + t_) * 64 + (d ^ ((t_ & 7) << 3))] = (_Float16)v;
                    } else {
                        pVT[(bh * 64 + d) * TPAD + ((t_ & ~63) | ((t_ & 63) ^ ((d & 7) << 3)))] = (_Float16)v;
                    }
                }
            }
        }
    }
}

// ---------------- fp16 MFMA flash attention, double-buffered K/V (unchanged) ----------------
__global__ __launch_bounds__(256) void attn_mfma(
    const _Float16* __restrict__ Q, const _Float16* __restrict__ Kp,
    const _Float16* __restrict__ VT, _Float16* __restrict__ wa) {
    __shared__ _Float16 lds[20480];  // 2 x (K[64][64] + VT[64][64]) + P[4][16][64] = 40 KiB
    int tid = threadIdx.x, wid = tid >> 6, lane = tid & 63;
    int qt = blockIdx.x, h = blockIdx.y, b = blockIdx.z;
    size_t bh = (size_t)b * NH + h;

    int qrow = qt * 64 + wid * 16 + (lane & 15);
    const _Float16* qb = Q + (bh * TPAD + qrow) * 64 + (lane >> 4) * 8;
    f16x8 qf[2];
    qf[0] = *(const f16x8*)qb;
    qf[1] = *(const f16x8*)(qb + 32);

    f32x4 oacc[4];
    #pragma unroll
    for (int dt = 0; dt < 4; ++dt) oacc[dt] = (f32x4)0.0f;
    float m[4] = {-1e30f, -1e30f, -1e30f, -1e30f};
    float lsum[4] = {0.f, 0.f, 0.f, 0.f};

    _Float16* pbase = &lds[16384 + wid * 1024];
    const _Float16* gK = Kp + (bh * TPAD + (wid & 1) * 32 + (lane >> 3)) * 64 + (lane & 7) * 8;
    const _Float16* gV = VT + (bh * 64 + (wid & 1) * 32 + (lane >> 3)) * TPAD + (lane & 7) * 8;
    int dstoff = (wid >> 1) * 4096 + (wid & 1) * 2048;

    #pragma unroll
    for (int i = 0; i < 4; ++i) {
        const _Float16* g = (wid < 2) ? (gK + (size_t)i * 8 * 64) : (gV + (size_t)i * 8 * TPAD);
        __builtin_amdgcn_global_load_lds(
            (const __attribute__((address_space(1))) void*)g,
            (__attribute__((address_space(3))) void*)(&lds[dstoff] + i * 512), 16, 0, 0);
    }
    __syncthreads();

    int cur = 0;
    for (int kt0 = 0; kt0 < TT; kt0 += 64) {
        if (kt0 + 64 < TT) {
            int nxt = kt0 + 64;
            #pragma unroll
            for (int i = 0; i < 4; ++i) {
                const _Float16* g = (wid < 2) ? (gK + (size_t)(nxt) * 64 + (size_t)i * 8 * 64)
                                              : (gV + nxt + (size_t)i * 8 * TPAD);
                __builtin_amdgcn_global_load_lds(
                    (const __attribute__((address_space(1))) void*)g,
                    (__attribute__((address_space(3))) void*)(&lds[(cur ^ 1) * 8192 + dstoff] + i * 512),
                    16, 0, 0);
            }
        }
        const _Float16* kbuf = &lds[cur * 8192];
        const _Float16* vbuf = &lds[cur * 8192 + 4096];

        f32x4 sacc[4];
        #pragma unroll
        for (int kt = 0; kt < 4; ++kt) sacc[kt] = (f32x4)0.0f;
        #pragma unroll
        for (int dstep = 0; dstep < 2; ++dstep) {
            #pragma unroll
            for (int kt = 0; kt < 4; ++kt) {
                int krow = kt * 16 + (lane & 15);
                int ko = (((dstep * 4 + (lane >> 4)) ^ (krow & 7)) << 3);
                f16x8 kb = *(const f16x8*)&kbuf[krow * 64 + ko];
                sacc[kt] = __builtin_amdgcn_mfma_f32_16x16x32_f16(qf[dstep], kb, sacc[kt], 0, 0, 0);
            }
        }
        #pragma unroll
        for (int kt = 0; kt < 4; ++kt) {
            int kcol = kt0 + kt * 16 + (lane & 15);
            if (kcol >= TT) {
                #pragma unroll
                for (int r = 0; r < 4; ++r) sacc[kt][r] = -1e30f;
            }
        }
        float mt[4];
        #pragma unroll
        for (int r = 0; r < 4; ++r)
            mt[r] = fmaxf(fmaxf(sacc[0][r], sacc[1][r]), fmaxf(sacc[2][r], sacc[3][r]));
        #pragma unroll
        for (int off = 1; off <= 8; off <<= 1) {
            #pragma unroll
            for (int r = 0; r < 4; ++r) mt[r] = fmaxf(mt[r], __shfl_xor(mt[r], off));
        }
        float corr[4];
        #pragma unroll
        for (int r = 0; r < 4; ++r) {
            float nm = fmaxf(m[r], mt[r]);
            corr[r] = __expf(m[r] - nm);
            m[r] = nm;
        }
        float rowsum[4] = {0.f, 0.f, 0.f, 0.f};
        #pragma unroll
        for (int kt = 0; kt < 4; ++kt) {
            #pragma unroll
            for (int r = 0; r < 4; ++r) {
                float p = __expf(sacc[kt][r] - m[r]);
                rowsum[r] += p;
                int q = (lane >> 4) * 4 + r;
                int kcol = kt * 16 + (lane & 15);
                pbase[q * 64 + (kcol ^ ((q & 7) << 3))] = (_Float16)p;
            }
        }
        #pragma unroll
        for (int off = 1; off <= 8; off <<= 1) {
            #pragma unroll
            for (int r = 0; r < 4; ++r) rowsum[r] += __shfl_xor(rowsum[r], off);
        }
        #pragma unroll
        for (int r = 0; r < 4; ++r) {
            lsum[r] = lsum[r] * corr[r] + rowsum[r];
            #pragma unroll
            for (int dt = 0; dt < 4; ++dt) oacc[dt][r] *= corr[r];
        }
        #pragma unroll
        for (int kc = 0; kc < 2; ++kc) {
            int q = lane & 15;
            int pko = (((kc * 4 + (lane >> 4)) ^ (q & 7)) << 3);
            f16x8 pa = *(const f16x8*)&pbase[q * 64 + pko];
            #pragma unroll
            for (int dt = 0; dt < 4; ++dt) {
                int drow = dt * 16 + (lane & 15);
                int vo = (((kc * 4 + (lane >> 4)) ^ (drow & 7)) << 3);
                f16x8 vb = *(const f16x8*)&vbuf[drow * 64 + vo];
                oacc[dt] = __builtin_amdgcn_mfma_f32_16x16x32_f16(pa, vb, oacc[dt], 0, 0, 0);
            }
        }
        __syncthreads();
        cur ^= 1;
    }

    // epilogue -> wa plane (4-way swizzle for GEMM consumption)
    #pragma unroll
    for (int r = 0; r < 4; ++r) {
        int t = qt * 64 + wid * 16 + (lane >> 4) * 4 + r;
        if (t >= TT) continue;
        float inv = 1.0f / lsum[r];
        size_t row = (size_t)b * TT + t;
        int sw = (int)(row & 3) << 3;
        size_t ro = row * DIM;
        #pragma unroll
        for (int dt = 0; dt < 4; ++dt) {
            int c = h * 64 + dt * 16 + (lane & 15);
            wa[ro + (c ^ sw)] = (_Float16)(oacc[dt][r] * inv);
        }
    }
}

// --------------------------------------------------------------------------------
extern "C" void kernel_launch(void* const* d_in, const int* in_sizes, int n_in,
                              void* d_out, int out_size, void* d_ws, size_t ws_size,
                              hipStream_t stream) {
    const float* x      = (const float*)d_in[0];
    const float* ln1_w  = (const float*)d_in[1];
    const float* ln1_b  = (const float*)d_in[2];
    const float* qkv_w  = (const float*)d_in[3];
    const float* qkv_b  = (const float*)d_in[4];
    const float* proj_w = (const float*)d_in[5];
    const float* proj_b = (const float*)d_in[6];
    const float* ln2_w  = (const float*)d_in[7];
    const float* ln2_b  = (const float*)d_in[8];
    const float* fc1_w  = (const float*)d_in[9];
    const float* fc1_b  = (const float*)d_in[10];
    const float* fc2_w  = (const float*)d_in[11];
    const float* fc2_b  = (const float*)d_in[12];
    float* out = (float*)d_out;

    const size_t P768  = (size_t)MPAD * 768;
    const size_t P3072 = (size_t)MPAD * 3072;
    const size_t PQKV  = (size_t)BB * NH * TPAD * 64;
    char* wsb = (char*)d_ws;
    auto alloc = [&](size_t bytes) -> char* {
        char* p = wsb;
        wsb += (bytes + 255) & ~(size_t)255;
        return p;
    };
    _Float16* h_p   = (_Float16*)alloc(P768 * 2);
    _Float16* wa_p  = (_Float16*)alloc(P768 * 2);
    float* x1 = (float*)alloc((size_t)BT * 768 * 4);
    _Float16* qkvT = (_Float16*)alloc((size_t)2304 * 768 * 2);
    _Float16* projT = (_Float16*)alloc((size_t)768 * 768 * 2);
    _Float16* fc1T = (_Float16*)alloc((size_t)3072 * 768 * 2);
    _Float16* fc2T = (_Float16*)alloc((size_t)768 * 3072 * 2);
    char* ubase = alloc(P3072 * 2 > 3 * PQKV * 2 ? P3072 * 2 : 3 * PQKV * 2);
    _Float16* pQ  = (_Float16*)ubase;
    _Float16* pK  = pQ + PQKV;
    _Float16* pVT = pK + PQKV;
    _Float16* hh  = (_Float16*)ubase;

    dim3 blk(256);
    int mt = (BT + 127) / 128;  // 73

    convert_wT<<<dim3(2304 / 64, 768 / 32), blk, 0, stream>>>(qkv_w, qkvT, 768, 2304);
    convert_wT<<<dim3(768 / 64, 768 / 32), blk, 0, stream>>>(proj_w, projT, 768, 768);
    convert_wT<<<dim3(3072 / 64, 768 / 32), blk, 0, stream>>>(fc1_w, fc1T, 768, 3072);
    convert_wT<<<dim3(768 / 64, 3072 / 32), blk, 0, stream>>>(fc2_w, fc2T, 3072, 768);

    // 1) h = LN1(x)
    ln_kernel<<<BT, blk, 0, stream>>>(x, ln1_w, ln1_b, h_p);
    // 2) qkv GEMM -> attention planes (Q scaled, K swizzled, V transposed)
    gemm_mfma<3><<<dim3(2304 / 128, mt), blk, 0, stream>>>(h_p, qkvT, qkv_b,
        nullptr, nullptr, nullptr, pQ, pK, pVT, BT, 2304, 768);
    // 3) wa = attention
    attn_mfma<<<dim3((TT + 63) / 64, NH, BB), blk, 0, stream>>>(pQ, pK, pVT, wa_p);
    // 4) x1 = x + wa @ proj_w + proj_b
    gemm_mfma<2><<<dim3(768 / 128, mt), blk, 0, stream>>>(wa_p, projT, proj_b,
        x, x1, nullptr, nullptr, nullptr, nullptr, BT, 768, 768);
    // 5) h = LN2(x1)
    ln_kernel<<<BT, blk, 0, stream>>>(x1, ln2_w, ln2_b, h_p);
    // 6) hh = gelu(h @ fc1_w + fc1_b)
    gemm_mfma<1><<<dim3(3072 / 128, mt), blk, 0, stream>>>(h_p, fc1T, fc1_b,
        nullptr, nullptr, hh, nullptr, nullptr, nullptr, BT, 3072, 768);
    // 7) out = x1 + hh @ fc2_w + fc2_b
    gemm_mfma<2><<<dim3(768 / 128, mt), blk, 0, stream>>>(hh, fc2T, fc2_b,
        x1, out, nullptr, nullptr, nullptr, nullptr, BT, 768, 3072);
}

// Round 12
// 475.722 us; speedup vs baseline: 1.0366x; 1.0366x over previous
//
#include <hip/hip_runtime.h>
#include <math.h>

#define DIM 768
#define NH 12
#define HIDDEN 3072
#define BB 16
#define TT 577
#define TPAD 640
#define BT (BB*TT)      // 9232
#define MPAD 9344       // 73*128

typedef _Float16 f16x8 __attribute__((ext_vector_type(8)));
typedef __attribute__((ext_vector_type(4))) float f32x4;

// ---------------- LayerNorm -> fp16 plane (8-way pre-swizzled) ----------------
__global__ __launch_bounds__(256) void ln_kernel(const float* __restrict__ x,
                                                 const float* __restrict__ w,
                                                 const float* __restrict__ b,
                                                 _Float16* __restrict__ oh) {
    int row = blockIdx.x;
    const float* xr = x + (size_t)row * DIM;
    int t = threadIdx.x;
    float v0 = xr[t], v1 = xr[t + 256], v2 = xr[t + 512];
    float s = v0 + v1 + v2;
    float sq = v0 * v0 + v1 * v1 + v2 * v2;
    __shared__ float red[8];
    int lane = t & 63, wid = t >> 6;
    #pragma unroll
    for (int off = 32; off; off >>= 1) {
        s  += __shfl_down(s, off);
        sq += __shfl_down(sq, off);
    }
    if (lane == 0) { red[wid] = s; red[4 + wid] = sq; }
    __syncthreads();
    if (t == 0) {
        float ts = red[0] + red[1] + red[2] + red[3];
        float tq = red[4] + red[5] + red[6] + red[7];
        float mu = ts * (1.0f / DIM);
        float var = tq * (1.0f / DIM) - mu * mu;
        red[0] = mu;
        red[1] = rsqrtf(var + 1e-6f);
    }
    __syncthreads();
    float mu = red[0], rstd = red[1];
    int sw = (row & 7) << 3;
    size_t ro = (size_t)row * DIM;
    #pragma unroll
    for (int e = 0; e < 3; ++e) {
        int c = t + e * 256;
        float v = (e == 0 ? v0 : (e == 1 ? v1 : v2));
        float val = (v - mu) * rstd * w[c] + b[c];
        oh[ro + (c ^ sw)] = (_Float16)val;
    }
}

// -------- weight convert: fp32 [K][N] -> fp16 [N][K], 8-way pre-swizzled --------
__global__ __launch_bounds__(256) void convert_wT(const float* __restrict__ src,
                                                  _Float16* __restrict__ dh,
                                                  int K, int N) {
    int n = blockIdx.x * 64 + (threadIdx.x & 63);
    int k0 = blockIdx.y * 32 + (threadIdx.x >> 6) * 8;
    f16x8 h8;
    #pragma unroll
    for (int j = 0; j < 8; ++j) h8[j] = (_Float16)src[(size_t)(k0 + j) * N + n];
    *(f16x8*)&dh[(size_t)n * K + (k0 ^ ((n & 7) << 3))] = h8;
}

// ---------------- fp16 MFMA GEMM, BK=64 dbuf + XCD remap + vector epilogue ----------------
// A [Mpad][K], B [N][K] fp16, both pre-swizzled (k ^ ((row&7)<<3)).
// EPI: 1 = GELU -> fp16 plane (LDS-transposed vector store), 2 = +resid fp32 out,
//      3 = QKV -> attention planes
template<int EPI>
__global__ __launch_bounds__(256) void gemm_mfma(
    const _Float16* __restrict__ A, const _Float16* __restrict__ B,
    const float* __restrict__ bias, const float* __restrict__ resid,
    float* __restrict__ C, _Float16* __restrict__ O,
    _Float16* __restrict__ pQ, _Float16* __restrict__ pK, _Float16* __restrict__ pVT,
    int M, int N, int K) {
    __shared__ _Float16 lds[2][2][128][64];  // [dbuf][A/B][128][64] = 64 KiB
    int tid = threadIdx.x;
    int wid = tid >> 6, lane = tid & 63;

    // XCD-aware bijective remap (m204): same-A-panel tiles -> same XCD L2
    int gx = gridDim.x;
    int nwg = gx * gridDim.y;
    int hw = blockIdx.y * gx + blockIdx.x;
    int xcd = hw & 7, loc = hw >> 3;
    int q = nwg >> 3, r = nwg & 7;
    int wg = (xcd < r ? xcd * (q + 1) : r * (q + 1) + (xcd - r) * q) + loc;
    int bxl = wg % gx, byl = wg / gx;

    int m0 = byl * 128, n0 = bxl * 128;
    int wr = wid >> 1, wc = wid & 1;

    // wave wid stages 64 rows (8 issues x 1 KiB, linear LDS dest)
    const _Float16* src = (wid < 2) ? A : B;
    int srow0 = ((wid < 2) ? m0 : n0) + (wid & 1) * 64;
    const _Float16* gbase = src + (size_t)(srow0 + (lane >> 3)) * K + (lane & 7) * 8;
    _Float16* lb[2] = { &lds[0][wid >> 1][(wid & 1) * 64][0],
                        &lds[1][wid >> 1][(wid & 1) * 64][0] };

    f32x4 acc[4][4];
    #pragma unroll
    for (int i = 0; i < 4; ++i)
        #pragma unroll
        for (int j = 0; j < 4; ++j) acc[i][j] = (f32x4)0.0f;

    const int nk = K >> 6;
    #pragma unroll
    for (int i = 0; i < 8; ++i)
        __builtin_amdgcn_global_load_lds(
            (const __attribute__((address_space(1))) void*)(gbase + (size_t)i * 8 * K),
            (__attribute__((address_space(3))) void*)(lb[0] + i * 512), 16, 0, 0);
    __syncthreads();

    int cur = 0;
    for (int ks = 0; ks < nk; ++ks) {
        if (ks + 1 < nk) {
            int k0 = (ks + 1) << 6;
            #pragma unroll
            for (int i = 0; i < 8; ++i)
                __builtin_amdgcn_global_load_lds(
                    (const __attribute__((address_space(1))) void*)(gbase + (size_t)i * 8 * K + k0),
                    (__attribute__((address_space(3))) void*)(lb[cur ^ 1] + i * 512), 16, 0, 0);
        }
        #pragma unroll
        for (int kk = 0; kk < 2; ++kk) {
            int so = (((kk * 4 + (lane >> 4)) ^ (lane & 7)) << 3);
            f16x8 af[4], bf[4];
            #pragma unroll
            for (int m = 0; m < 4; ++m)
                af[m] = *(const f16x8*)&lds[cur][0][wr * 64 + m * 16 + (lane & 15)][so];
            #pragma unroll
            for (int n = 0; n < 4; ++n)
                bf[n] = *(const f16x8*)&lds[cur][1][wc * 64 + n * 16 + (lane & 15)][so];
            #pragma unroll
            for (int m = 0; m < 4; ++m)
                #pragma unroll
                for (int n = 0; n < 4; ++n)
                    acc[m][n] = __builtin_amdgcn_mfma_f32_16x16x32_f16(af[m], bf[n], acc[m][n], 0, 0, 0);
        }
        __syncthreads();
        cur ^= 1;
    }

    if (EPI == 1) {
        // GELU -> LDS transpose (stride 136: 16B-aligned rows) -> f16x8 stores
        _Float16* eb = &lds[0][0][0][0];
        int rl0 = wr * 64 + (lane >> 4) * 4;
        int cl0 = wc * 64 + (lane & 15);
        #pragma unroll
        for (int mi = 0; mi < 4; ++mi) {
            #pragma unroll
            for (int ni = 0; ni < 4; ++ni) {
                int cl = cl0 + ni * 16;
                float bsv = bias[n0 + cl];
                #pragma unroll
                for (int r4 = 0; r4 < 4; ++r4) {
                    int rl = rl0 + mi * 16 + r4;
                    float v = acc[mi][ni][r4] + bsv;
                    v = v / (1.0f + __expf(-1.5957691216f * (v + 0.044715f * v * v * v)));
                    eb[rl * 136 + cl] = (_Float16)v;
                }
            }
        }
        __syncthreads();
        int rl = tid >> 1;
        int rowg = m0 + rl;
        if (rowg < M) {
            int sw = (rowg & 7) << 3;
            int c0 = (tid & 1) * 64;
            size_t rb = (size_t)rowg * N;
            #pragma unroll
            for (int j = 0; j < 8; ++j) {
                f16x8 v = *(const f16x8*)&eb[rl * 136 + c0 + j * 8];
                *(f16x8*)&O[rb + ((n0 + c0 + j * 8) ^ sw)] = v;
            }
        }
        return;
    }

    // EPI 2 / 3: per-element epilogue
    int rbase = m0 + wr * 64 + (lane >> 4) * 4;
    int cbase = n0 + wc * 64 + (lane & 15);
    #pragma unroll
    for (int mi = 0; mi < 4; ++mi) {
        #pragma unroll
        for (int ni = 0; ni < 4; ++ni) {
            int c = cbase + ni * 16;
            float bsv = bias[c];
            #pragma unroll
            for (int r4 = 0; r4 < 4; ++r4) {
                int r = rbase + mi * 16 + r4;
                if (r >= M) continue;
                float v = acc[mi][ni][r4] + bsv;
                if (EPI == 2) {
                    v += resid[(size_t)r * N + c];
                    C[(size_t)r * N + c] = v;
                } else {  // EPI == 3: scatter to attention planes
                    int b_ = r / TT, t_ = r - b_ * TT;
                    int which = c / DIM, cc = c - which * DIM;
                    int head = cc >> 6, d = cc & 63;
                    size_t bh = (size_t)b_ * NH + head;
                    if (which == 0) {
                        pQ[(bh * TPAD + t_) * 64 + d] = (_Float16)(v * 0.125f);
                    } else if (which == 1) {
                        pK[(bh * TPAD + t_) * 64 + (d ^ ((t_ & 7) << 3))] = (_Float16)v;
                    } else {
                        pVT[(bh * 64 + d) * TPAD + ((t_ & ~63) | ((t_ & 63) ^ ((d & 7) << 3)))] = (_Float16)v;
                    }
                }
            }
        }
    }
}

// ---------------- fp16 MFMA flash attention, double-buffered K/V ----------------
__global__ __launch_bounds__(256) void attn_mfma(
    const _Float16* __restrict__ Q, const _Float16* __restrict__ Kp,
    const _Float16* __restrict__ VT, _Float16* __restrict__ wa) {
    __shared__ _Float16 lds[20480];  // 2 x (K[64][64] + VT[64][64]) + P[4][16][64] = 40 KiB
    int tid = threadIdx.x, wid = tid >> 6, lane = tid & 63;
    int qt = blockIdx.x, h = blockIdx.y, b = blockIdx.z;
    size_t bh = (size_t)b * NH + h;

    int qrow = qt * 64 + wid * 16 + (lane & 15);
    const _Float16* qb = Q + (bh * TPAD + qrow) * 64 + (lane >> 4) * 8;
    f16x8 qf[2];
    qf[0] = *(const f16x8*)qb;
    qf[1] = *(const f16x8*)(qb + 32);

    f32x4 oacc[4];
    #pragma unroll
    for (int dt = 0; dt < 4; ++dt) oacc[dt] = (f32x4)0.0f;
    float m[4] = {-1e30f, -1e30f, -1e30f, -1e30f};
    float lsum[4] = {0.f, 0.f, 0.f, 0.f};

    _Float16* pbase = &lds[16384 + wid * 1024];
    const _Float16* gK = Kp + (bh * TPAD + (wid & 1) * 32 + (lane >> 3)) * 64 + (lane & 7) * 8;
    const _Float16* gV = VT + (bh * 64 + (wid & 1) * 32 + (lane >> 3)) * TPAD + (lane & 7) * 8;
    int dstoff = (wid >> 1) * 4096 + (wid & 1) * 2048;

    #pragma unroll
    for (int i = 0; i < 4; ++i) {
        const _Float16* g = (wid < 2) ? (gK + (size_t)i * 8 * 64) : (gV + (size_t)i * 8 * TPAD);
        __builtin_amdgcn_global_load_lds(
            (const __attribute__((address_space(1))) void*)g,
            (__attribute__((address_space(3))) void*)(&lds[dstoff] + i * 512), 16, 0, 0);
    }
    __syncthreads();

    int cur = 0;
    for (int kt0 = 0; kt0 < TT; kt0 += 64) {
        if (kt0 + 64 < TT) {
            int nxt = kt0 + 64;
            #pragma unroll
            for (int i = 0; i < 4; ++i) {
                const _Float16* g = (wid < 2) ? (gK + (size_t)(nxt) * 64 + (size_t)i * 8 * 64)
                                              : (gV + nxt + (size_t)i * 8 * TPAD);
                __builtin_amdgcn_global_load_lds(
                    (const __attribute__((address_space(1))) void*)g,
                    (__attribute__((address_space(3))) void*)(&lds[(cur ^ 1) * 8192 + dstoff] + i * 512),
                    16, 0, 0);
            }
        }
        const _Float16* kbuf = &lds[cur * 8192];
        const _Float16* vbuf = &lds[cur * 8192 + 4096];

        f32x4 sacc[4];
        #pragma unroll
        for (int kt = 0; kt < 4; ++kt) sacc[kt] = (f32x4)0.0f;
        #pragma unroll
        for (int dstep = 0; dstep < 2; ++dstep) {
            #pragma unroll
            for (int kt = 0; kt < 4; ++kt) {
                int krow = kt * 16 + (lane & 15);
                int ko = (((dstep * 4 + (lane >> 4)) ^ (krow & 7)) << 3);
                f16x8 kb = *(const f16x8*)&kbuf[krow * 64 + ko];
                sacc[kt] = __builtin_amdgcn_mfma_f32_16x16x32_f16(qf[dstep], kb, sacc[kt], 0, 0, 0);
            }
        }
        #pragma unroll
        for (int kt = 0; kt < 4; ++kt) {
            int kcol = kt0 + kt * 16 + (lane & 15);
            if (kcol >= TT) {
                #pragma unroll
                for (int r = 0; r < 4; ++r) sacc[kt][r] = -1e30f;
            }
        }
        float mt[4];
        #pragma unroll
        for (int r = 0; r < 4; ++r)
            mt[r] = fmaxf(fmaxf(sacc[0][r], sacc[1][r]), fmaxf(sacc[2][r], sacc[3][r]));
        #pragma unroll
        for (int off = 1; off <= 8; off <<= 1) {
            #pragma unroll
            for (int r = 0; r < 4; ++r) mt[r] = fmaxf(mt[r], __shfl_xor(mt[r], off));
        }
        float corr[4];
        #pragma unroll
        for (int r = 0; r < 4; ++r) {
            float nm = fmaxf(m[r], mt[r]);
            corr[r] = __expf(m[r] - nm);
            m[r] = nm;
        }
        float rowsum[4] = {0.f, 0.f, 0.f, 0.f};
        #pragma unroll
        for (int kt = 0; kt < 4; ++kt) {
            #pragma unroll
            for (int r = 0; r < 4; ++r) {
                float p = __expf(sacc[kt][r] - m[r]);
                rowsum[r] += p;
                int qq = (lane >> 4) * 4 + r;
                int kcol = kt * 16 + (lane & 15);
                pbase[qq * 64 + (kcol ^ ((qq & 7) << 3))] = (_Float16)p;
            }
        }
        #pragma unroll
        for (int off = 1; off <= 8; off <<= 1) {
            #pragma unroll
            for (int r = 0; r < 4; ++r) rowsum[r] += __shfl_xor(rowsum[r], off);
        }
        #pragma unroll
        for (int r = 0; r < 4; ++r) {
            lsum[r] = lsum[r] * corr[r] + rowsum[r];
            #pragma unroll
            for (int dt = 0; dt < 4; ++dt) oacc[dt][r] *= corr[r];
        }
        #pragma unroll
        for (int kc = 0; kc < 2; ++kc) {
            int qq = lane & 15;
            int pko = (((kc * 4 + (lane >> 4)) ^ (qq & 7)) << 3);
            f16x8 pa = *(const f16x8*)&pbase[qq * 64 + pko];
            #pragma unroll
            for (int dt = 0; dt < 4; ++dt) {
                int drow = dt * 16 + (lane & 15);
                int vo = (((kc * 4 + (lane >> 4)) ^ (drow & 7)) << 3);
                f16x8 vb = *(const f16x8*)&vbuf[drow * 64 + vo];
                oacc[dt] = __builtin_amdgcn_mfma_f32_16x16x32_f16(pa, vb, oacc[dt], 0, 0, 0);
            }
        }
        __syncthreads();
        cur ^= 1;
    }

    #pragma unroll
    for (int r = 0; r < 4; ++r) {
        int t = qt * 64 + wid * 16 + (lane >> 4) * 4 + r;
        if (t >= TT) continue;
        float inv = 1.0f / lsum[r];
        size_t row = (size_t)b * TT + t;
        int sw = (int)(row & 7) << 3;
        size_t ro = row * DIM;
        #pragma unroll
        for (int dt = 0; dt < 4; ++dt) {
            int c = h * 64 + dt * 16 + (lane & 15);
            wa[ro + (c ^ sw)] = (_Float16)(oacc[dt][r] * inv);
        }
    }
}

// --------------------------------------------------------------------------------
extern "C" void kernel_launch(void* const* d_in, const int* in_sizes, int n_in,
                              void* d_out, int out_size, void* d_ws, size_t ws_size,
                              hipStream_t stream) {
    const float* x      = (const float*)d_in[0];
    const float* ln1_w  = (const float*)d_in[1];
    const float* ln1_b  = (const float*)d_in[2];
    const float* qkv_w  = (const float*)d_in[3];
    const float* qkv_b  = (const float*)d_in[4];
    const float* proj_w = (const float*)d_in[5];
    const float* proj_b = (const float*)d_in[6];
    const float* ln2_w  = (const float*)d_in[7];
    const float* ln2_b  = (const float*)d_in[8];
    const float* fc1_w  = (const float*)d_in[9];
    const float* fc1_b  = (const float*)d_in[10];
    const float* fc2_w  = (const float*)d_in[11];
    const float* fc2_b  = (const float*)d_in[12];
    float* out = (float*)d_out;

    const size_t P768  = (size_t)MPAD * 768;
    const size_t P3072 = (size_t)MPAD * 3072;
    const size_t PQKV  = (size_t)BB * NH * TPAD * 64;
    char* wsb = (char*)d_ws;
    auto alloc = [&](size_t bytes) -> char* {
        char* p = wsb;
        wsb += (bytes + 255) & ~(size_t)255;
        return p;
    };
    _Float16* h_p   = (_Float16*)alloc(P768 * 2);
    _Float16* wa_p  = (_Float16*)alloc(P768 * 2);
    float* x1 = (float*)alloc((size_t)BT * 768 * 4);
    _Float16* qkvT = (_Float16*)alloc((size_t)2304 * 768 * 2);
    _Float16* projT = (_Float16*)alloc((size_t)768 * 768 * 2);
    _Float16* fc1T = (_Float16*)alloc((size_t)3072 * 768 * 2);
    _Float16* fc2T = (_Float16*)alloc((size_t)768 * 3072 * 2);
    char* ubase = alloc(P3072 * 2 > 3 * PQKV * 2 ? P3072 * 2 : 3 * PQKV * 2);
    _Float16* pQ  = (_Float16*)ubase;
    _Float16* pK  = pQ + PQKV;
    _Float16* pVT = pK + PQKV;
    _Float16* hh  = (_Float16*)ubase;

    dim3 blk(256);
    int mt = (BT + 127) / 128;  // 73

    convert_wT<<<dim3(2304 / 64, 768 / 32), blk, 0, stream>>>(qkv_w, qkvT, 768, 2304);
    convert_wT<<<dim3(768 / 64, 768 / 32), blk, 0, stream>>>(proj_w, projT, 768, 768);
    convert_wT<<<dim3(3072 / 64, 768 / 32), blk, 0, stream>>>(fc1_w, fc1T, 768, 3072);
    convert_wT<<<dim3(768 / 64, 3072 / 32), blk, 0, stream>>>(fc2_w, fc2T, 3072, 768);

    // 1) h = LN1(x)
    ln_kernel<<<BT, blk, 0, stream>>>(x, ln1_w, ln1_b, h_p);
    // 2) qkv GEMM -> attention planes (Q scaled, K swizzled, V transposed)
    gemm_mfma<3><<<dim3(2304 / 128, mt), blk, 0, stream>>>(h_p, qkvT, qkv_b,
        nullptr, nullptr, nullptr, pQ, pK, pVT, BT, 2304, 768);
    // 3) wa = attention
    attn_mfma<<<dim3((TT + 63) / 64, NH, BB), blk, 0, stream>>>(pQ, pK, pVT, wa_p);
    // 4) x1 = x + wa @ proj_w + proj_b
    gemm_mfma<2><<<dim3(768 / 128, mt), blk, 0, stream>>>(wa_p, projT, proj_b,
        x, x1, nullptr, nullptr, nullptr, nullptr, BT, 768, 768);
    // 5) h = LN2(x1)
    ln_kernel<<<BT, blk, 0, stream>>>(x1, ln2_w, ln2_b, h_p);
    // 6) hh = gelu(h @ fc1_w + fc1_b)
    gemm_mfma<1><<<dim3(3072 / 128, mt), blk, 0, stream>>>(h_p, fc1T, fc1_b,
        nullptr, nullptr, hh, nullptr, nullptr, nullptr, BT, 3072, 768);
    // 7) out = x1 + hh @ fc2_w + fc2_b
    gemm_mfma<2><<<dim3(768 / 128, mt), blk, 0, stream>>>(hh, fc2T, fc2_b,
        x1, out, nullptr, nullptr, nullptr, nullptr, BT, 768, 3072);
}